// Round 7
// baseline (253.592 us; speedup 1.0000x reference)
//
#include <hip/hip_runtime.h>
#include <hip/hip_bf16.h>
#include <stdint.h>

typedef unsigned int u32;

#define IJ 16384
#define NQ 1024
#define NB 2
#define KP 256

// ---------------- Threefry-2x32 (JAX-compatible, 20 rounds) ----------------
__device__ __forceinline__ void tf2x32(u32 k0, u32 k1, u32& x0, u32& x1) {
  u32 kx = k0 ^ k1 ^ 0x1BD11BDAu;
#define TFR(r) { x0 += x1; x1 = (x1 << (r)) | (x1 >> (32 - (r))); x1 ^= x0; }
  x0 += k0; x1 += k1;
  TFR(13) TFR(15) TFR(26) TFR(6)
  x0 += k1; x1 += kx + 1u;
  TFR(17) TFR(29) TFR(16) TFR(24)
  x0 += kx; x1 += k0 + 2u;
  TFR(13) TFR(15) TFR(26) TFR(6)
  x0 += k0; x1 += k1 + 3u;
  TFR(17) TFR(29) TFR(16) TFR(24)
  x0 += k1; x1 += kx + 4u;
  TFR(13) TFR(15) TFR(26) TFR(6)
  x0 += kx; x1 += k0 + 5u;
#undef TFR
}

// threefry_partitionable=True (JAX >= 0.5 default) semantics:
// split(key)[i]            = enc_key(0, i)
// random_bits(key,32,…)[i] = w0 ^ w1 of enc_key(hi32(i), lo32(i))
__device__ __forceinline__ void tf_subkey(u32 k0, u32 k1, u32 i, u32& s0, u32& s1) {
  u32 x0 = 0u, x1 = i;
  tf2x32(k0, k1, x0, x1);
  s0 = x0; s1 = x1;
}

__device__ __forceinline__ u32 tf_xorbits(u32 k0, u32 k1, u32 i) {
  u32 x0 = 0u, x1 = i;
  tf2x32(k0, k1, x0, x1);
  return x0 ^ x1;
}

__device__ __forceinline__ void derive_keys(int seed, u32& kq0, u32& kq1,
                                            u32& km0, u32& km1) {
  u32 k0 = 0u;
  u32 k1 = (u32)seed;
  tf_subkey(k0, k1, 0u, kq0, kq1);
  tf_subkey(k0, k1, 1u, km0, km1);
}

// JAX uniform(minval=tiny, maxval=1) -> gumbel.  g in [-4.4697, 15.9425].
__device__ __forceinline__ float gumbel_from_bits(u32 w) {
  const float tiny = 1.17549435e-38f;
  float fl = __uint_as_float((w >> 9) | 0x3f800000u) - 1.0f;
  float u = fl * (1.0f - tiny) + tiny;
  u = fmaxf(tiny, u);
  return -logf(-logf(u));
}

// bool input accessor: harness may stage numpy bool as 1-byte or as int32
__device__ __forceinline__ bool read_bool(const void* p, int idx, int is32) {
  return is32 ? (((const int*)p)[idx] != 0)
              : (((const unsigned char*)p)[idx] != 0);
}

// ---------------- setup: n_idx, bool-width detect, num_valid, zero row_max -
__global__ void setup_kernel(const void* __restrict__ valid_q,
                             const int* __restrict__ seedp,
                             float* __restrict__ row_max,
                             float* __restrict__ num_valid,
                             int* __restrict__ n_idx,
                             int* __restrict__ bool_is32) {
  __shared__ int sred[256];
  __shared__ int is32_s;
  const int blk = blockIdx.x, tid = threadIdx.x;
  if (blk < 4) {
    // randint(kq,(2,512),0,1024): k1,k2 = split(kq); multiplier = 0
    //  -> n_idx = random_bits(k2) % 1024
    int s = blk * 256 + tid;  // 0..1023
    u32 kq0, kq1, km0, km1;
    derive_keys(seedp[0], kq0, kq1, km0, km1);
    u32 l0, l1;  // k2 = enc(kq, (0,1))
    tf_subkey(kq0, kq1, 1u, l0, l1);
    u32 w = tf_xorbits(l0, l1, (u32)s);
    n_idx[s] = (int)(w & 1023u);
  } else if (blk == 4) {
    // detect bool storage width from the first 2048 bytes of valid_q
    const unsigned char* vb = (const unsigned char*)valid_q;
    int ones = 0;
    for (int i = tid; i < 2048; i += 256) ones += (vb[i] == 1) ? 1 : 0;
    sred[tid] = ones;
    __syncthreads();
    for (int off = 128; off > 0; off >>= 1) {
      if (tid < off) sred[tid] += sred[tid + off];
      __syncthreads();
    }
    if (tid == 0) {
      is32_s = (sred[0] < 1152) ? 1 : 0;
      bool_is32[0] = is32_s;
    }
    __syncthreads();
    const int is32 = is32_s;
    for (int b = 0; b < 2; ++b) {
      int acc = 0;
      for (int i = tid; i < NQ; i += 256)
        acc += read_bool(valid_q, b * NQ + i, is32) ? 1 : 0;
      sred[tid] = acc;
      __syncthreads();
      for (int off = 128; off > 0; off >>= 1) {
        if (tid < off) sred[tid] += sred[tid + off];
        __syncthreads();
      }
      if (tid == 0) {
        float nv = (float)sred[0];
        num_valid[b] = nv < 1.f ? 1.f : nv;
      }
      __syncthreads();
    }
  } else {
    for (int i = (blk - 5) * 256 + tid; i < NB * NQ; i += 768) row_max[i] = 0.f;
  }
}

// ---------------- GEMM: sim = relu(f_q . f_map^T) * exp(T), fused row max --
__global__ __launch_bounds__(256) void gemm_kernel(
    const float* __restrict__ f_q, const float* __restrict__ f_map,
    const float* __restrict__ temp, float* __restrict__ sim,
    float* __restrict__ row_max) {
  __shared__ float As[32][64];
  __shared__ float Bs[32][256];
  __shared__ float rmax[64];
  const int tid = threadIdx.x;
  const int b = blockIdx.z;
  const int n0 = blockIdx.y * 64;
  const int ij0 = blockIdx.x * 256;

  {  // stage A (transpose to d-major): 64x32 floats
    const float4* gA = (const float4*)(f_q + ((size_t)b * NQ + n0) * 32);
    for (int q = tid; q < 512; q += 256) {
      float4 v = gA[q];
      int nn = q >> 3, dg = (q & 7) << 2;
      As[dg][nn] = v.x; As[dg + 1][nn] = v.y; As[dg + 2][nn] = v.z; As[dg + 3][nn] = v.w;
    }
  }
  {  // stage B (transpose to d-major): 256x32 floats
    const float4* gB = (const float4*)(f_map + ((size_t)b * IJ + ij0) * 32);
    for (int q = tid; q < 2048; q += 256) {
      float4 v = gB[q];
      int jj = q >> 3, dg = (q & 7) << 2;
      Bs[dg][jj] = v.x; Bs[dg + 1][jj] = v.y; Bs[dg + 2][jj] = v.z; Bs[dg + 3][jj] = v.w;
    }
  }
  if (tid < 64) rmax[tid] = 0.f;
  __syncthreads();

  const int ty = tid >> 5, tx = tid & 31;
  float acc[2][2][4][4] = {};
#pragma unroll 8
  for (int d = 0; d < 32; ++d) {
    float4 a0 = *(const float4*)&As[d][ty << 2];
    float4 a1 = *(const float4*)&As[d][(ty << 2) + 32];
    float4 b0 = *(const float4*)&Bs[d][tx << 2];
    float4 b1 = *(const float4*)&Bs[d][(tx << 2) + 128];
    float av[2][4] = {{a0.x, a0.y, a0.z, a0.w}, {a1.x, a1.y, a1.z, a1.w}};
    float bv[2][4] = {{b0.x, b0.y, b0.z, b0.w}, {b1.x, b1.y, b1.z, b1.w}};
#pragma unroll
    for (int rg = 0; rg < 2; ++rg)
#pragma unroll
      for (int cg = 0; cg < 2; ++cg)
#pragma unroll
        for (int r = 0; r < 4; ++r)
#pragma unroll
          for (int c = 0; c < 4; ++c)
            acc[rg][cg][r][c] = fmaf(av[rg][r], bv[cg][c], acc[rg][cg][r][c]);
  }

  const float et = expf(temp[0]);
#pragma unroll
  for (int rg = 0; rg < 2; ++rg) {
#pragma unroll
    for (int r = 0; r < 4; ++r) {
      const int lrow = rg * 32 + (ty << 2) + r;
      const int n = n0 + lrow;
      float* base = sim + ((size_t)b * NQ + n) * IJ + ij0;
      float rm = 0.f;
#pragma unroll
      for (int cg = 0; cg < 2; ++cg) {
        float4 o;
        o.x = fmaxf(acc[rg][cg][r][0], 0.f) * et;
        o.y = fmaxf(acc[rg][cg][r][1], 0.f) * et;
        o.z = fmaxf(acc[rg][cg][r][2], 0.f) * et;
        o.w = fmaxf(acc[rg][cg][r][3], 0.f) * et;
        *(float4*)(base + cg * 128 + (tx << 2)) = o;
        rm = fmaxf(rm, fmaxf(fmaxf(o.x, o.y), fmaxf(o.z, o.w)));
      }
      atomicMax((u32*)&rmax[lrow], __float_as_uint(rm));  // nonneg floats
    }
  }
  __syncthreads();
  if (tid < 64)
    atomicMax((u32*)&row_max[(size_t)b * NQ + n0 + tid], __float_as_uint(rmax[tid]));
}

// ---------------- per-row sum of exp(sim - m) ------------------------------
__global__ __launch_bounds__(256) void sumexp_kernel(
    const float* __restrict__ sim, const float* __restrict__ row_max,
    float* __restrict__ row_sumexp) {
  __shared__ float sred[256];
  const int row = blockIdx.x, tid = threadIdx.x;
  const float m = row_max[row];
  const float4* p = (const float4*)(sim + (size_t)row * IJ);
  float s = 0.f;
  for (int q = tid; q < IJ / 4; q += 256) {
    float4 v = p[q];
    s += expf(v.x - m); s += expf(v.y - m); s += expf(v.z - m); s += expf(v.w - m);
  }
  sred[tid] = s;
  __syncthreads();
  for (int off = 128; off > 0; off >>= 1) {
    if (tid < off) sred[tid] += sred[tid + off];
    __syncthreads();
  }
  if (tid == 0) row_sumexp[row] = sred[0];
}

// ---------------- categorical: R4 full-scan loop + inline skip -------------
// Identical loop structure, expressions, and tie semantics to the passing
// Round-4 kernel; the ONLY change is skipping the threefry+transcendental
// work when r <= m - 25.  Any winner must satisfy r >= m - 20.42
// (gumbel range [-4.4697, 15.9425] + 1e-20-floor analysis), so a margin of
// 25 makes skipped entries unable to win or tie; evaluated entries produce
// bit-identical values in the same per-thread visit order as Round 4.
__global__ __launch_bounds__(256) void cat_kernel(
    const float* __restrict__ sim, const float* __restrict__ row_max,
    const float* __restrict__ row_sumexp, const float* __restrict__ num_valid,
    const int* __restrict__ n_idx, const int* __restrict__ seedp,
    int* __restrict__ m_flat) {
  __shared__ float sv[2][256];
  __shared__ int si[2][256];
  const int t = blockIdx.x, tid = threadIdx.x;
  u32 kq0, kq1, km0, km1;
  derive_keys(seedp[0], kq0, kq1, km0, km1);
  const int nA = n_idx[t], nB = n_idx[512 + t];
  const float m0 = row_max[nA], s0 = row_sumexp[nA];
  const float m1 = row_max[NQ + nB], s1 = row_sumexp[NQ + nB];
  const float nv0 = num_valid[0], nv1 = num_valid[1];
  const float thA = m0 - 25.0f;
  const float thB = m1 - 25.0f;
  const float* r0 = sim + (size_t)nA * IJ;
  const float* r1 = sim + (size_t)(NQ + nB) * IJ;
  float b0v = -1e30f, b1v = -1e30f;
  int b0i = 0, b1i = 0;
  for (int f = tid; f < IJ; f += 256) {
    float ra = r0[f];
    if (ra > thA) {
      u32 w0 = tf_xorbits(km0, km1, (u32)(t * IJ + f));
      float g0 = gumbel_from_bits(w0);
      float e0 = expf(ra - m0);
      float v0 = logf((e0 / s0) / nv0 + 1e-20f) + g0;
      if (v0 > b0v) { b0v = v0; b0i = f; }
    }
    float rb = r1[f];
    if (rb > thB) {
      u32 w1 = tf_xorbits(km0, km1, (u32)(t * IJ + f) + 8388608u);  // +2^23
      float g1 = gumbel_from_bits(w1);
      float e1 = expf(rb - m1);
      float v1 = logf((e1 / s1) / nv1 + 1e-20f) + g1;
      if (v1 > b1v) { b1v = v1; b1i = f; }
    }
  }
  sv[0][tid] = b0v; si[0][tid] = b0i;
  sv[1][tid] = b1v; si[1][tid] = b1i;
  __syncthreads();
  for (int off = 128; off > 0; off >>= 1) {
    if (tid < off) {
#pragma unroll
      for (int q = 0; q < 2; ++q) {
        float v2 = sv[q][tid + off];
        int i2 = si[q][tid + off];
        if (v2 > sv[q][tid] || (v2 == sv[q][tid] && i2 < si[q][tid])) {
          sv[q][tid] = v2; si[q][tid] = i2;
        }
      }
    }
    __syncthreads();
  }
  if (tid == 0) { m_flat[t] = si[0][0]; m_flat[512 + t] = si[1][0]; }
}

// ---------------- pose hypotheses (R, t) -----------------------------------
__global__ void pose_kernel(const float* __restrict__ q_xy,
                            const int* __restrict__ n_idx,
                            const int* __restrict__ m_flat,
                            float4* __restrict__ poses) {
  const int idx = blockIdx.x * 256 + threadIdx.x;  // 0..511
  if (idx >= NB * KP) return;
  const int b = idx >> 8, k = idx & 255;
  const int t0 = b * 512 + 2 * k, t1 = t0 + 1;
  const int na = n_idx[t0], nb = n_idx[t1];
  const float2 q0 = ((const float2*)q_xy)[(size_t)b * NQ + na];
  const float2 q1 = ((const float2*)q_xy)[(size_t)b * NQ + nb];
  const int ma = m_flat[t0], mb = m_flat[t1];
  const float m0x = ((float)(ma >> 7) + 0.5f) * 0.5f;
  const float m0y = ((float)(ma & 127) + 0.5f) * 0.5f;
  const float m1x = ((float)(mb >> 7) + 0.5f) * 0.5f;
  const float m1y = ((float)(mb & 127) + 0.5f) * 0.5f;
  const float dqx = q1.x - q0.x, dqy = q1.y - q0.y;
  const float dmx = m1x - m0x, dmy = m1y - m0y;
  const float theta = atan2f(dmy, dmx) - atan2f(dqy, dqx);
  const float c = cosf(theta), s = sinf(theta);
  const float tx = m0x - (c * q0.x - s * q0.y);
  const float ty = m0y - (s * q0.x + c * q0.y);
  poses[idx] = make_float4(c, s, tx, ty);
}

// ---------------- score every pose -----------------------------------------
__global__ __launch_bounds__(256) void score_kernel(
    const float* __restrict__ sim, const float* __restrict__ q_xy,
    const void* __restrict__ valid_q, const void* __restrict__ valid_map,
    const float* __restrict__ num_valid, const float4* __restrict__ poses,
    const int* __restrict__ bool_is32, float* __restrict__ out) {
  __shared__ float sred[256];
  const int idx = blockIdx.x;  // b*256 + k
  const int tid = threadIdx.x;
  const int b = idx >> 8;
  const int is32 = bool_is32[0];
  const float4 P = poses[idx];
  float acc = 0.f;
  for (int n = tid; n < NQ; n += 256) {
    float2 q = ((const float2*)q_xy)[(size_t)b * NQ + n];
    float px = P.x * q.x - P.y * q.y + P.z;
    float py = P.y * q.x + P.x * q.y + P.w;
    int ii = (int)floorf(px * 2.0f);  // / CELL (=0.5) is exact *2
    int jj = (int)floorf(py * 2.0f);
    bool inb = (ii >= 0) & (ii < 128) & (jj >= 0) & (jj < 128);
    int ic = min(max(ii, 0), 127), jc = min(max(jj, 0), 127);
    int flat = (ic << 7) + jc;
    bool msk = read_bool(valid_q, b * NQ + n, is32) && inb &&
               read_bool(valid_map, b * IJ + flat, is32);
    if (msk) acc += sim[((size_t)(b * NQ + n)) * IJ + flat];
  }
  sred[tid] = acc;
  __syncthreads();
  for (int off = 128; off > 0; off >>= 1) {
    if (tid < off) sred[tid] += sred[tid + off];
    __syncthreads();
  }
  if (tid == 0) out[idx] = sred[0] / num_valid[b];
}

// ---------------------------------------------------------------------------
extern "C" void kernel_launch(void* const* d_in, const int* in_sizes, int n_in,
                              void* d_out, int out_size, void* d_ws,
                              size_t ws_size, hipStream_t stream) {
  const float* f_q = (const float*)d_in[0];
  const float* f_map = (const float*)d_in[1];
  const float* q_xy = (const float*)d_in[2];
  const float* temp = (const float*)d_in[3];
  const void* valid_q = d_in[4];    // numpy bool: width auto-detected
  const void* valid_map = d_in[5];  // numpy bool: width auto-detected
  const int* seedp = (const int*)d_in[6];
  float* out = (float*)d_out;

  char* ws = (char*)d_ws;
  const size_t SIM_BYTES = (size_t)NB * NQ * IJ * 4;  // 134217728
  float* sim = (float*)ws;
  float* row_max = (float*)(ws + SIM_BYTES);
  float* row_sumexp = (float*)(ws + SIM_BYTES + 8192);
  float* num_valid = (float*)(ws + SIM_BYTES + 16384);
  int* n_idx = (int*)(ws + SIM_BYTES + 16448);
  int* m_flat = (int*)(ws + SIM_BYTES + 20544);
  float4* poses = (float4*)(ws + SIM_BYTES + 24640);
  int* bool_is32 = (int*)(ws + SIM_BYTES + 32832);

  setup_kernel<<<8, 256, 0, stream>>>(valid_q, seedp, row_max, num_valid,
                                      n_idx, bool_is32);
  gemm_kernel<<<dim3(64, 16, 2), 256, 0, stream>>>(f_q, f_map, temp, sim, row_max);
  sumexp_kernel<<<NB * NQ, 256, 0, stream>>>(sim, row_max, row_sumexp);
  cat_kernel<<<512, 256, 0, stream>>>(sim, row_max, row_sumexp, num_valid,
                                      n_idx, seedp, m_flat);
  pose_kernel<<<2, 256, 0, stream>>>(q_xy, n_idx, m_flat, poses);
  score_kernel<<<NB * KP, 256, 0, stream>>>(sim, q_xy, valid_q, valid_map,
                                            num_valid, poses, bool_is32, out);
}

// Round 8
// 208.458 us; speedup vs baseline: 1.2165x; 1.2165x over previous
//
#include <hip/hip_runtime.h>
#include <hip/hip_bf16.h>
#include <stdint.h>

typedef unsigned int u32;

#define IJ 16384
#define NQ 1024
#define NB 2
#define KP 256
#define NSEG 8
#define SEGW 2048  // IJ / NSEG

// ---------------- Threefry-2x32 (JAX-compatible, 20 rounds) ----------------
__device__ __forceinline__ void tf2x32(u32 k0, u32 k1, u32& x0, u32& x1) {
  u32 kx = k0 ^ k1 ^ 0x1BD11BDAu;
#define TFR(r) { x0 += x1; x1 = (x1 << (r)) | (x1 >> (32 - (r))); x1 ^= x0; }
  x0 += k0; x1 += k1;
  TFR(13) TFR(15) TFR(26) TFR(6)
  x0 += k1; x1 += kx + 1u;
  TFR(17) TFR(29) TFR(16) TFR(24)
  x0 += kx; x1 += k0 + 2u;
  TFR(13) TFR(15) TFR(26) TFR(6)
  x0 += k0; x1 += k1 + 3u;
  TFR(17) TFR(29) TFR(16) TFR(24)
  x0 += k1; x1 += kx + 4u;
  TFR(13) TFR(15) TFR(26) TFR(6)
  x0 += kx; x1 += k0 + 5u;
#undef TFR
}

// threefry_partitionable=True (JAX >= 0.5 default) semantics:
// split(key)[i]            = enc_key(0, i)
// random_bits(key,32,…)[i] = w0 ^ w1 of enc_key(hi32(i), lo32(i))
__device__ __forceinline__ void tf_subkey(u32 k0, u32 k1, u32 i, u32& s0, u32& s1) {
  u32 x0 = 0u, x1 = i;
  tf2x32(k0, k1, x0, x1);
  s0 = x0; s1 = x1;
}

__device__ __forceinline__ u32 tf_xorbits(u32 k0, u32 k1, u32 i) {
  u32 x0 = 0u, x1 = i;
  tf2x32(k0, k1, x0, x1);
  return x0 ^ x1;
}

__device__ __forceinline__ void derive_keys(int seed, u32& kq0, u32& kq1,
                                            u32& km0, u32& km1) {
  u32 k0 = 0u;
  u32 k1 = (u32)seed;
  tf_subkey(k0, k1, 0u, kq0, kq1);
  tf_subkey(k0, k1, 1u, km0, km1);
}

// JAX uniform(minval=tiny, maxval=1) -> gumbel.  g in [-4.4697, 15.9425].
__device__ __forceinline__ float gumbel_from_bits(u32 w) {
  const float tiny = 1.17549435e-38f;
  float fl = __uint_as_float((w >> 9) | 0x3f800000u) - 1.0f;
  float u = fl * (1.0f - tiny) + tiny;
  u = fmaxf(tiny, u);
  return -logf(-logf(u));
}

// bool input accessor: harness may stage numpy bool as 1-byte or as int32
__device__ __forceinline__ bool read_bool(const void* p, int idx, int is32) {
  return is32 ? (((const int*)p)[idx] != 0)
              : (((const unsigned char*)p)[idx] != 0);
}

// ---------------- setup: n_idx, bool-width detect, num_valid, zero row_max -
__global__ void setup_kernel(const void* __restrict__ valid_q,
                             const int* __restrict__ seedp,
                             float* __restrict__ row_max,
                             float* __restrict__ num_valid,
                             int* __restrict__ n_idx,
                             int* __restrict__ bool_is32) {
  __shared__ int sred[256];
  __shared__ int is32_s;
  const int blk = blockIdx.x, tid = threadIdx.x;
  if (blk < 4) {
    // randint(kq,(2,512),0,1024): k1,k2 = split(kq); multiplier = 0
    //  -> n_idx = random_bits(k2) % 1024
    int s = blk * 256 + tid;  // 0..1023
    u32 kq0, kq1, km0, km1;
    derive_keys(seedp[0], kq0, kq1, km0, km1);
    u32 l0, l1;  // k2 = enc(kq, (0,1))
    tf_subkey(kq0, kq1, 1u, l0, l1);
    u32 w = tf_xorbits(l0, l1, (u32)s);
    n_idx[s] = (int)(w & 1023u);
  } else if (blk == 4) {
    // detect bool storage width from the first 2048 bytes of valid_q
    const unsigned char* vb = (const unsigned char*)valid_q;
    int ones = 0;
    for (int i = tid; i < 2048; i += 256) ones += (vb[i] == 1) ? 1 : 0;
    sred[tid] = ones;
    __syncthreads();
    for (int off = 128; off > 0; off >>= 1) {
      if (tid < off) sred[tid] += sred[tid + off];
      __syncthreads();
    }
    if (tid == 0) {
      is32_s = (sred[0] < 1152) ? 1 : 0;
      bool_is32[0] = is32_s;
    }
    __syncthreads();
    const int is32 = is32_s;
    for (int b = 0; b < 2; ++b) {
      int acc = 0;
      for (int i = tid; i < NQ; i += 256)
        acc += read_bool(valid_q, b * NQ + i, is32) ? 1 : 0;
      sred[tid] = acc;
      __syncthreads();
      for (int off = 128; off > 0; off >>= 1) {
        if (tid < off) sred[tid] += sred[tid + off];
        __syncthreads();
      }
      if (tid == 0) {
        float nv = (float)sred[0];
        num_valid[b] = nv < 1.f ? 1.f : nv;
      }
      __syncthreads();
    }
  } else {
    for (int i = (blk - 5) * 256 + tid; i < NB * NQ; i += 768) row_max[i] = 0.f;
  }
}

// ---------------- GEMM: sim = relu(f_q . f_map^T) * exp(T), fused row max --
__global__ __launch_bounds__(256) void gemm_kernel(
    const float* __restrict__ f_q, const float* __restrict__ f_map,
    const float* __restrict__ temp, float* __restrict__ sim,
    float* __restrict__ row_max) {
  __shared__ float As[32][64];
  __shared__ float Bs[32][256];
  __shared__ float rmax[64];
  const int tid = threadIdx.x;
  const int b = blockIdx.z;
  const int n0 = blockIdx.y * 64;
  const int ij0 = blockIdx.x * 256;

  {  // stage A (transpose to d-major): 64x32 floats
    const float4* gA = (const float4*)(f_q + ((size_t)b * NQ + n0) * 32);
    for (int q = tid; q < 512; q += 256) {
      float4 v = gA[q];
      int nn = q >> 3, dg = (q & 7) << 2;
      As[dg][nn] = v.x; As[dg + 1][nn] = v.y; As[dg + 2][nn] = v.z; As[dg + 3][nn] = v.w;
    }
  }
  {  // stage B (transpose to d-major): 256x32 floats
    const float4* gB = (const float4*)(f_map + ((size_t)b * IJ + ij0) * 32);
    for (int q = tid; q < 2048; q += 256) {
      float4 v = gB[q];
      int jj = q >> 3, dg = (q & 7) << 2;
      Bs[dg][jj] = v.x; Bs[dg + 1][jj] = v.y; Bs[dg + 2][jj] = v.z; Bs[dg + 3][jj] = v.w;
    }
  }
  if (tid < 64) rmax[tid] = 0.f;
  __syncthreads();

  const int ty = tid >> 5, tx = tid & 31;
  float acc[2][2][4][4] = {};
#pragma unroll 8
  for (int d = 0; d < 32; ++d) {
    float4 a0 = *(const float4*)&As[d][ty << 2];
    float4 a1 = *(const float4*)&As[d][(ty << 2) + 32];
    float4 b0 = *(const float4*)&Bs[d][tx << 2];
    float4 b1 = *(const float4*)&Bs[d][(tx << 2) + 128];
    float av[2][4] = {{a0.x, a0.y, a0.z, a0.w}, {a1.x, a1.y, a1.z, a1.w}};
    float bv[2][4] = {{b0.x, b0.y, b0.z, b0.w}, {b1.x, b1.y, b1.z, b1.w}};
#pragma unroll
    for (int rg = 0; rg < 2; ++rg)
#pragma unroll
      for (int cg = 0; cg < 2; ++cg)
#pragma unroll
        for (int r = 0; r < 4; ++r)
#pragma unroll
          for (int c = 0; c < 4; ++c)
            acc[rg][cg][r][c] = fmaf(av[rg][r], bv[cg][c], acc[rg][cg][r][c]);
  }

  const float et = expf(temp[0]);
#pragma unroll
  for (int rg = 0; rg < 2; ++rg) {
#pragma unroll
    for (int r = 0; r < 4; ++r) {
      const int lrow = rg * 32 + (ty << 2) + r;
      const int n = n0 + lrow;
      float* base = sim + ((size_t)b * NQ + n) * IJ + ij0;
      float rm = 0.f;
#pragma unroll
      for (int cg = 0; cg < 2; ++cg) {
        float4 o;
        o.x = fmaxf(acc[rg][cg][r][0], 0.f) * et;
        o.y = fmaxf(acc[rg][cg][r][1], 0.f) * et;
        o.z = fmaxf(acc[rg][cg][r][2], 0.f) * et;
        o.w = fmaxf(acc[rg][cg][r][3], 0.f) * et;
        *(float4*)(base + cg * 128 + (tx << 2)) = o;
        rm = fmaxf(rm, fmaxf(fmaxf(o.x, o.y), fmaxf(o.z, o.w)));
      }
      atomicMax((u32*)&rmax[lrow], __float_as_uint(rm));  // nonneg floats
    }
  }
  __syncthreads();
  if (tid < 64)
    atomicMax((u32*)&row_max[(size_t)b * NQ + n0 + tid], __float_as_uint(rmax[tid]));
}

// ---------------- per-row sum of exp(sim - m) ------------------------------
__global__ __launch_bounds__(256) void sumexp_kernel(
    const float* __restrict__ sim, const float* __restrict__ row_max,
    float* __restrict__ row_sumexp) {
  __shared__ float sred[256];
  const int row = blockIdx.x, tid = threadIdx.x;
  const float m = row_max[row];
  const float4* p = (const float4*)(sim + (size_t)row * IJ);
  float s = 0.f;
  for (int q = tid; q < IJ / 4; q += 256) {
    float4 v = p[q];
    s += expf(v.x - m); s += expf(v.y - m); s += expf(v.z - m); s += expf(v.w - m);
  }
  sred[tid] = s;
  __syncthreads();
  for (int off = 128; off > 0; off >>= 1) {
    if (tid < off) sred[tid] += sred[tid + off];
    __syncthreads();
  }
  if (tid == 0) row_sumexp[row] = sred[0];
}

// ---------------- categorical, segmented: same math as Round 7 -------------
// Each block scans 1/8 of both rows for pose-pair t with the exact R7
// expression tree + m-25 skip (proven exact); per-segment (best v, best i)
// go to ws; cat_reduce combines with the same (v, tie->min idx) lattice, so
// the global argmax is identical to R7's.
__global__ __launch_bounds__(256) void cat_seg_kernel(
    const float* __restrict__ sim, const float* __restrict__ row_max,
    const float* __restrict__ row_sumexp, const float* __restrict__ num_valid,
    const int* __restrict__ n_idx, const int* __restrict__ seedp,
    float* __restrict__ segv, int* __restrict__ segi) {
  __shared__ float sv[2][256];
  __shared__ int si[2][256];
  const int seg = blockIdx.x;  // 0..NSEG-1
  const int t = blockIdx.y;    // 0..511
  const int tid = threadIdx.x;
  u32 kq0, kq1, km0, km1;
  derive_keys(seedp[0], kq0, kq1, km0, km1);
  const int nA = n_idx[t], nB = n_idx[512 + t];
  const float m0 = row_max[nA], s0 = row_sumexp[nA];
  const float m1 = row_max[NQ + nB], s1 = row_sumexp[NQ + nB];
  const float nv0 = num_valid[0], nv1 = num_valid[1];
  const float thA = m0 - 25.0f;
  const float thB = m1 - 25.0f;
  const float* r0 = sim + (size_t)nA * IJ + seg * SEGW;
  const float* r1 = sim + (size_t)(NQ + nB) * IJ + seg * SEGW;

  float bv0 = -1e30f, bv1 = -1e30f;
  int bi0 = 0, bi1 = 0;
#pragma unroll
  for (int k = 0; k < 2; ++k) {
    const int l = tid + k * 256;       // float4 index within segment
    const int fl = seg * SEGW + l * 4; // f within row (ascending per thread)
    float4 va = ((const float4*)r0)[l];
    float4 vb = ((const float4*)r1)[l];
    const float ra[4] = {va.x, va.y, va.z, va.w};
    const float rb[4] = {vb.x, vb.y, vb.z, vb.w};
#pragma unroll
    for (int c = 0; c < 4; ++c) {
      if (ra[c] > thA) {
        u32 w = tf_xorbits(km0, km1, (u32)(t * IJ + fl + c));
        float g = gumbel_from_bits(w);
        float e = expf(ra[c] - m0);
        float v = logf((e / s0) / nv0 + 1e-20f) + g;
        if (v > bv0) { bv0 = v; bi0 = fl + c; }
      }
      if (rb[c] > thB) {
        u32 w = tf_xorbits(km0, km1, (u32)(t * IJ + fl + c) + 8388608u);  // +2^23
        float g = gumbel_from_bits(w);
        float e = expf(rb[c] - m1);
        float v = logf((e / s1) / nv1 + 1e-20f) + g;
        if (v > bv1) { bv1 = v; bi1 = fl + c; }
      }
    }
  }
  sv[0][tid] = bv0; si[0][tid] = bi0;
  sv[1][tid] = bv1; si[1][tid] = bi1;
  __syncthreads();
  for (int off = 128; off > 0; off >>= 1) {
    if (tid < off) {
#pragma unroll
      for (int q = 0; q < 2; ++q) {
        float v2 = sv[q][tid + off];
        int i2 = si[q][tid + off];
        if (v2 > sv[q][tid] || (v2 == sv[q][tid] && i2 < si[q][tid])) {
          sv[q][tid] = v2; si[q][tid] = i2;
        }
      }
    }
    __syncthreads();
  }
  if (tid == 0) {
    segv[(0 * 512 + t) * NSEG + seg] = sv[0][0];
    segi[(0 * 512 + t) * NSEG + seg] = si[0][0];
    segv[(1 * 512 + t) * NSEG + seg] = sv[1][0];
    segi[(1 * 512 + t) * NSEG + seg] = si[1][0];
  }
}

__global__ void cat_reduce_kernel(const float* __restrict__ segv,
                                  const int* __restrict__ segi,
                                  int* __restrict__ m_flat) {
  const int idx = blockIdx.x * 256 + threadIdx.x;  // 0..1023 = b*512 + t
  if (idx >= NB * 512) return;
  float bv = -1e30f;
  int bi = 0;
#pragma unroll
  for (int s = 0; s < NSEG; ++s) {
    float v = segv[idx * NSEG + s];
    int i = segi[idx * NSEG + s];
    if (v > bv || (v == bv && i < bi)) { bv = v; bi = i; }
  }
  m_flat[idx] = bi;
}

// ---------------- pose hypotheses (R, t) -----------------------------------
__global__ void pose_kernel(const float* __restrict__ q_xy,
                            const int* __restrict__ n_idx,
                            const int* __restrict__ m_flat,
                            float4* __restrict__ poses) {
  const int idx = blockIdx.x * 256 + threadIdx.x;  // 0..511
  if (idx >= NB * KP) return;
  const int b = idx >> 8, k = idx & 255;
  const int t0 = b * 512 + 2 * k, t1 = t0 + 1;
  const int na = n_idx[t0], nb = n_idx[t1];
  const float2 q0 = ((const float2*)q_xy)[(size_t)b * NQ + na];
  const float2 q1 = ((const float2*)q_xy)[(size_t)b * NQ + nb];
  const int ma = m_flat[t0], mb = m_flat[t1];
  const float m0x = ((float)(ma >> 7) + 0.5f) * 0.5f;
  const float m0y = ((float)(ma & 127) + 0.5f) * 0.5f;
  const float m1x = ((float)(mb >> 7) + 0.5f) * 0.5f;
  const float m1y = ((float)(mb & 127) + 0.5f) * 0.5f;
  const float dqx = q1.x - q0.x, dqy = q1.y - q0.y;
  const float dmx = m1x - m0x, dmy = m1y - m0y;
  const float theta = atan2f(dmy, dmx) - atan2f(dqy, dqx);
  const float c = cosf(theta), s = sinf(theta);
  const float tx = m0x - (c * q0.x - s * q0.y);
  const float ty = m0y - (s * q0.x + c * q0.y);
  poses[idx] = make_float4(c, s, tx, ty);
}

// ---------------- score every pose -----------------------------------------
__global__ __launch_bounds__(256) void score_kernel(
    const float* __restrict__ sim, const float* __restrict__ q_xy,
    const void* __restrict__ valid_q, const void* __restrict__ valid_map,
    const float* __restrict__ num_valid, const float4* __restrict__ poses,
    const int* __restrict__ bool_is32, float* __restrict__ out) {
  __shared__ float sred[256];
  const int idx = blockIdx.x;  // b*256 + k
  const int tid = threadIdx.x;
  const int b = idx >> 8;
  const int is32 = bool_is32[0];
  const float4 P = poses[idx];
  float acc = 0.f;
  for (int n = tid; n < NQ; n += 256) {
    float2 q = ((const float2*)q_xy)[(size_t)b * NQ + n];
    float px = P.x * q.x - P.y * q.y + P.z;
    float py = P.y * q.x + P.x * q.y + P.w;
    int ii = (int)floorf(px * 2.0f);  // / CELL (=0.5) is exact *2
    int jj = (int)floorf(py * 2.0f);
    bool inb = (ii >= 0) & (ii < 128) & (jj >= 0) & (jj < 128);
    int ic = min(max(ii, 0), 127), jc = min(max(jj, 0), 127);
    int flat = (ic << 7) + jc;
    bool msk = read_bool(valid_q, b * NQ + n, is32) && inb &&
               read_bool(valid_map, b * IJ + flat, is32);
    if (msk) acc += sim[((size_t)(b * NQ + n)) * IJ + flat];
  }
  sred[tid] = acc;
  __syncthreads();
  for (int off = 128; off > 0; off >>= 1) {
    if (tid < off) sred[tid] += sred[tid + off];
    __syncthreads();
  }
  if (tid == 0) out[idx] = sred[0] / num_valid[b];
}

// ---------------------------------------------------------------------------
extern "C" void kernel_launch(void* const* d_in, const int* in_sizes, int n_in,
                              void* d_out, int out_size, void* d_ws,
                              size_t ws_size, hipStream_t stream) {
  const float* f_q = (const float*)d_in[0];
  const float* f_map = (const float*)d_in[1];
  const float* q_xy = (const float*)d_in[2];
  const float* temp = (const float*)d_in[3];
  const void* valid_q = d_in[4];    // numpy bool: width auto-detected
  const void* valid_map = d_in[5];  // numpy bool: width auto-detected
  const int* seedp = (const int*)d_in[6];
  float* out = (float*)d_out;

  char* ws = (char*)d_ws;
  const size_t SIM_BYTES = (size_t)NB * NQ * IJ * 4;  // 134217728
  float* sim = (float*)ws;
  float* row_max = (float*)(ws + SIM_BYTES);
  float* row_sumexp = (float*)(ws + SIM_BYTES + 8192);
  float* num_valid = (float*)(ws + SIM_BYTES + 16384);
  int* n_idx = (int*)(ws + SIM_BYTES + 16448);
  int* m_flat = (int*)(ws + SIM_BYTES + 20544);
  float4* poses = (float4*)(ws + SIM_BYTES + 24640);
  int* bool_is32 = (int*)(ws + SIM_BYTES + 32832);
  float* segv = (float*)(ws + SIM_BYTES + 36864);   // 2*512*8 floats = 32 KB
  int* segi = (int*)(ws + SIM_BYTES + 69632);       // 32 KB

  setup_kernel<<<8, 256, 0, stream>>>(valid_q, seedp, row_max, num_valid,
                                      n_idx, bool_is32);
  gemm_kernel<<<dim3(64, 16, 2), 256, 0, stream>>>(f_q, f_map, temp, sim, row_max);
  sumexp_kernel<<<NB * NQ, 256, 0, stream>>>(sim, row_max, row_sumexp);
  cat_seg_kernel<<<dim3(NSEG, 512), 256, 0, stream>>>(
      sim, row_max, row_sumexp, num_valid, n_idx, seedp, segv, segi);
  cat_reduce_kernel<<<4, 256, 0, stream>>>(segv, segi, m_flat);
  pose_kernel<<<2, 256, 0, stream>>>(q_xy, n_idx, m_flat, poses);
  score_kernel<<<NB * KP, 256, 0, stream>>>(sim, q_xy, valid_q, valid_map,
                                            num_valid, poses, bool_is32, out);
}

// Round 9
// 166.803 us; speedup vs baseline: 1.5203x; 1.2497x over previous
//
#include <hip/hip_runtime.h>
#include <hip/hip_bf16.h>
#include <stdint.h>

typedef unsigned int u32;

#define IJ 16384
#define NQ 1024
#define NB 2
#define KP 256
#define NSEG 8
#define SEGW 2048  // IJ / NSEG

// ---------------- Threefry-2x32 (JAX-compatible, 20 rounds) ----------------
__device__ __forceinline__ void tf2x32(u32 k0, u32 k1, u32& x0, u32& x1) {
  u32 kx = k0 ^ k1 ^ 0x1BD11BDAu;
#define TFR(r) { x0 += x1; x1 = (x1 << (r)) | (x1 >> (32 - (r))); x1 ^= x0; }
  x0 += k0; x1 += k1;
  TFR(13) TFR(15) TFR(26) TFR(6)
  x0 += k1; x1 += kx + 1u;
  TFR(17) TFR(29) TFR(16) TFR(24)
  x0 += kx; x1 += k0 + 2u;
  TFR(13) TFR(15) TFR(26) TFR(6)
  x0 += k0; x1 += k1 + 3u;
  TFR(17) TFR(29) TFR(16) TFR(24)
  x0 += k1; x1 += kx + 4u;
  TFR(13) TFR(15) TFR(26) TFR(6)
  x0 += kx; x1 += k0 + 5u;
#undef TFR
}

// threefry_partitionable=True (JAX >= 0.5 default) semantics:
// split(key)[i]            = enc_key(0, i)
// random_bits(key,32,…)[i] = w0 ^ w1 of enc_key(hi32(i), lo32(i))
__device__ __forceinline__ void tf_subkey(u32 k0, u32 k1, u32 i, u32& s0, u32& s1) {
  u32 x0 = 0u, x1 = i;
  tf2x32(k0, k1, x0, x1);
  s0 = x0; s1 = x1;
}

__device__ __forceinline__ u32 tf_xorbits(u32 k0, u32 k1, u32 i) {
  u32 x0 = 0u, x1 = i;
  tf2x32(k0, k1, x0, x1);
  return x0 ^ x1;
}

__device__ __forceinline__ void derive_keys(int seed, u32& kq0, u32& kq1,
                                            u32& km0, u32& km1) {
  u32 k0 = 0u;
  u32 k1 = (u32)seed;
  tf_subkey(k0, k1, 0u, kq0, kq1);
  tf_subkey(k0, k1, 1u, km0, km1);
}

// JAX uniform(minval=tiny, maxval=1) -> gumbel.
// g in [-4.4697, 16.64]; winner bound r >= m - 21.11 (threshold m-25 is safe).
__device__ __forceinline__ float gumbel_from_bits(u32 w) {
  const float tiny = 1.17549435e-38f;
  float fl = __uint_as_float((w >> 9) | 0x3f800000u) - 1.0f;
  float u = fl * (1.0f - tiny) + tiny;
  u = fmaxf(tiny, u);
  return -logf(-logf(u));
}

// bool input accessor: harness may stage numpy bool as 1-byte or as int32
__device__ __forceinline__ bool read_bool(const void* p, int idx, int is32) {
  return is32 ? (((const int*)p)[idx] != 0)
              : (((const unsigned char*)p)[idx] != 0);
}

// ---------------- setup: n_idx, bool-width detect, num_valid, zero row_max -
__global__ void setup_kernel(const void* __restrict__ valid_q,
                             const int* __restrict__ seedp,
                             float* __restrict__ row_max,
                             float* __restrict__ num_valid,
                             int* __restrict__ n_idx,
                             int* __restrict__ bool_is32) {
  __shared__ int sred[256];
  __shared__ int is32_s;
  const int blk = blockIdx.x, tid = threadIdx.x;
  if (blk < 4) {
    // randint(kq,(2,512),0,1024): k1,k2 = split(kq); multiplier = 0
    //  -> n_idx = random_bits(k2) % 1024
    int s = blk * 256 + tid;  // 0..1023
    u32 kq0, kq1, km0, km1;
    derive_keys(seedp[0], kq0, kq1, km0, km1);
    u32 l0, l1;  // k2 = enc(kq, (0,1))
    tf_subkey(kq0, kq1, 1u, l0, l1);
    u32 w = tf_xorbits(l0, l1, (u32)s);
    n_idx[s] = (int)(w & 1023u);
  } else if (blk == 4) {
    // detect bool storage width from the first 2048 bytes of valid_q
    const unsigned char* vb = (const unsigned char*)valid_q;
    int ones = 0;
    for (int i = tid; i < 2048; i += 256) ones += (vb[i] == 1) ? 1 : 0;
    sred[tid] = ones;
    __syncthreads();
    for (int off = 128; off > 0; off >>= 1) {
      if (tid < off) sred[tid] += sred[tid + off];
      __syncthreads();
    }
    if (tid == 0) {
      is32_s = (sred[0] < 1152) ? 1 : 0;
      bool_is32[0] = is32_s;
    }
    __syncthreads();
    const int is32 = is32_s;
    for (int b = 0; b < 2; ++b) {
      int acc = 0;
      for (int i = tid; i < NQ; i += 256)
        acc += read_bool(valid_q, b * NQ + i, is32) ? 1 : 0;
      sred[tid] = acc;
      __syncthreads();
      for (int off = 128; off > 0; off >>= 1) {
        if (tid < off) sred[tid] += sred[tid + off];
        __syncthreads();
      }
      if (tid == 0) {
        float nv = (float)sred[0];
        num_valid[b] = nv < 1.f ? 1.f : nv;
      }
      __syncthreads();
    }
  } else {
    for (int i = (blk - 5) * 256 + tid; i < NB * NQ; i += 768) row_max[i] = 0.f;
  }
}

// ---------------- GEMM: sim = relu(.)·e^T, fused row-max + row Σe^r --------
// Per-row-per-tile Σ expf(val) is reduced deterministically (fixed per-thread
// order + fixed shfl tree) into rowsum_part[row][tile]; sumexp_reduce then
// computes s = (Σ_tiles) · e^(-m).  (≈1e-7 rel vs old two-pass s.)
__global__ __launch_bounds__(256) void gemm_kernel(
    const float* __restrict__ f_q, const float* __restrict__ f_map,
    const float* __restrict__ temp, float* __restrict__ sim,
    float* __restrict__ row_max, float* __restrict__ rowsum_part) {
  __shared__ float As[32][64];
  __shared__ float Bs[32][256];
  __shared__ float rmax[64];
  const int tid = threadIdx.x;
  const int b = blockIdx.z;
  const int n0 = blockIdx.y * 64;
  const int ij0 = blockIdx.x * 256;

  {  // stage A (transpose to d-major): 64x32 floats
    const float4* gA = (const float4*)(f_q + ((size_t)b * NQ + n0) * 32);
    for (int q = tid; q < 512; q += 256) {
      float4 v = gA[q];
      int nn = q >> 3, dg = (q & 7) << 2;
      As[dg][nn] = v.x; As[dg + 1][nn] = v.y; As[dg + 2][nn] = v.z; As[dg + 3][nn] = v.w;
    }
  }
  {  // stage B (transpose to d-major): 256x32 floats
    const float4* gB = (const float4*)(f_map + ((size_t)b * IJ + ij0) * 32);
    for (int q = tid; q < 2048; q += 256) {
      float4 v = gB[q];
      int jj = q >> 3, dg = (q & 7) << 2;
      Bs[dg][jj] = v.x; Bs[dg + 1][jj] = v.y; Bs[dg + 2][jj] = v.z; Bs[dg + 3][jj] = v.w;
    }
  }
  if (tid < 64) rmax[tid] = 0.f;
  __syncthreads();

  const int ty = tid >> 5, tx = tid & 31;
  float acc[2][2][4][4] = {};
#pragma unroll 8
  for (int d = 0; d < 32; ++d) {
    float4 a0 = *(const float4*)&As[d][ty << 2];
    float4 a1 = *(const float4*)&As[d][(ty << 2) + 32];
    float4 b0 = *(const float4*)&Bs[d][tx << 2];
    float4 b1 = *(const float4*)&Bs[d][(tx << 2) + 128];
    float av[2][4] = {{a0.x, a0.y, a0.z, a0.w}, {a1.x, a1.y, a1.z, a1.w}};
    float bv[2][4] = {{b0.x, b0.y, b0.z, b0.w}, {b1.x, b1.y, b1.z, b1.w}};
#pragma unroll
    for (int rg = 0; rg < 2; ++rg)
#pragma unroll
      for (int cg = 0; cg < 2; ++cg)
#pragma unroll
        for (int r = 0; r < 4; ++r)
#pragma unroll
          for (int c = 0; c < 4; ++c)
            acc[rg][cg][r][c] = fmaf(av[rg][r], bv[cg][c], acc[rg][cg][r][c]);
  }

  const float et = expf(temp[0]);
#pragma unroll
  for (int rg = 0; rg < 2; ++rg) {
#pragma unroll
    for (int r = 0; r < 4; ++r) {
      const int lrow = rg * 32 + (ty << 2) + r;
      const int n = n0 + lrow;
      float* base = sim + ((size_t)b * NQ + n) * IJ + ij0;
      float rm = 0.f;
      float se = 0.f;
#pragma unroll
      for (int cg = 0; cg < 2; ++cg) {
        float4 o;
        o.x = fmaxf(acc[rg][cg][r][0], 0.f) * et;
        o.y = fmaxf(acc[rg][cg][r][1], 0.f) * et;
        o.z = fmaxf(acc[rg][cg][r][2], 0.f) * et;
        o.w = fmaxf(acc[rg][cg][r][3], 0.f) * et;
        *(float4*)(base + cg * 128 + (tx << 2)) = o;
        rm = fmaxf(rm, fmaxf(fmaxf(o.x, o.y), fmaxf(o.z, o.w)));
        se += expf(o.x); se += expf(o.y); se += expf(o.z); se += expf(o.w);
      }
      atomicMax((u32*)&rmax[lrow], __float_as_uint(rm));  // nonneg floats
      // deterministic 32-lane reduction of se across tx (same wave half)
#pragma unroll
      for (int off = 16; off > 0; off >>= 1) se += __shfl_down(se, off, 32);
      if (tx == 0)
        rowsum_part[((size_t)(b * NQ + n)) * 64 + blockIdx.x] = se;
    }
  }
  __syncthreads();
  if (tid < 64)
    atomicMax((u32*)&row_max[(size_t)b * NQ + n0 + tid], __float_as_uint(rmax[tid]));
}

// ---------------- row_sumexp[row] = (Σ_tiles rowsum_part) * e^(-m) ---------
__global__ void sumexp_reduce_kernel(const float* __restrict__ rowsum_part,
                                     const float* __restrict__ row_max,
                                     float* __restrict__ row_sumexp) {
  const int row = blockIdx.x * 256 + threadIdx.x;  // 0..2047
  if (row >= NB * NQ) return;
  const float* p = rowsum_part + (size_t)row * 64;
  float s = 0.f;
#pragma unroll
  for (int t = 0; t < 64; ++t) s += p[t];  // fixed order: deterministic
  row_sumexp[row] = s * expf(-row_max[row]);
}

// ---------------- categorical, segmented + LDS candidate compaction --------
// Phase 1 compacts candidate indices (r > m-25; winner bound r >= m-21.11)
// into an LDS list capped at SEGW (cannot overflow: segment has SEGW elems).
// Phase 2 evaluates the exact R7 expression tree densely on the list.
// (max v, tie -> min f) lattice => global argmax identical to R7.
__global__ __launch_bounds__(256) void cat_seg_kernel(
    const float* __restrict__ sim, const float* __restrict__ row_max,
    const float* __restrict__ row_sumexp, const float* __restrict__ num_valid,
    const int* __restrict__ n_idx, const int* __restrict__ seedp,
    float* __restrict__ segv, int* __restrict__ segi) {
  __shared__ unsigned short cand[2][SEGW];
  __shared__ int ccount[2];
  __shared__ u32 keys[2];
  __shared__ float sv[2][256];
  __shared__ int si[2][256];
  const int seg = blockIdx.x;  // 0..NSEG-1
  const int t = blockIdx.y;    // 0..511
  const int tid = threadIdx.x;
  if (tid == 0) {
    u32 kq0, kq1, km0, km1;
    derive_keys(seedp[0], kq0, kq1, km0, km1);
    keys[0] = km0; keys[1] = km1;
    ccount[0] = 0; ccount[1] = 0;
  }
  __syncthreads();

  const int nA = n_idx[t], nB = n_idx[512 + t];
  const float m0 = row_max[nA], s0 = row_sumexp[nA];
  const float m1 = row_max[NQ + nB], s1 = row_sumexp[NQ + nB];
  const float nv0 = num_valid[0], nv1 = num_valid[1];
  const float thA = m0 - 25.0f;
  const float thB = m1 - 25.0f;
  const float* r0 = sim + (size_t)nA * IJ + seg * SEGW;
  const float* r1 = sim + (size_t)(NQ + nB) * IJ + seg * SEGW;

  // phase 1: compact candidates into LDS (local segment offsets, u16)
#pragma unroll
  for (int k = 0; k < 2; ++k) {
    const int l = tid + k * 256;  // float4 index within segment
    const int lf = l * 4;         // local element offset
    float4 va = ((const float4*)r0)[l];
    float4 vb = ((const float4*)r1)[l];
    const float ra[4] = {va.x, va.y, va.z, va.w};
    const float rb[4] = {vb.x, vb.y, vb.z, vb.w};
#pragma unroll
    for (int c = 0; c < 4; ++c) {
      if (ra[c] > thA) { int p = atomicAdd(&ccount[0], 1); cand[0][p] = (unsigned short)(lf + c); }
      if (rb[c] > thB) { int p = atomicAdd(&ccount[1], 1); cand[1][p] = (unsigned short)(lf + c); }
    }
  }
  __syncthreads();

  // phase 2: dense eval of candidates, exact R7 formula
  const u32 km0 = keys[0], km1 = keys[1];
  const int c0 = ccount[0], c1 = ccount[1];
  const int fbase = seg * SEGW;
  float bv0 = -1e30f, bv1 = -1e30f;
  int bi0 = IJ, bi1 = IJ;
  for (int c = tid; c < c0; c += 256) {
    int f = fbase + (int)cand[0][c];
    u32 w = tf_xorbits(km0, km1, (u32)(t * IJ + f));
    float g = gumbel_from_bits(w);
    float e = expf(r0[f - fbase] - m0);
    float v = logf((e / s0) / nv0 + 1e-20f) + g;
    if (v > bv0 || (v == bv0 && f < bi0)) { bv0 = v; bi0 = f; }
  }
  for (int c = tid; c < c1; c += 256) {
    int f = fbase + (int)cand[1][c];
    u32 w = tf_xorbits(km0, km1, (u32)(t * IJ + f) + 8388608u);  // +2^23
    float g = gumbel_from_bits(w);
    float e = expf(r1[f - fbase] - m1);
    float v = logf((e / s1) / nv1 + 1e-20f) + g;
    if (v > bv1 || (v == bv1 && f < bi1)) { bv1 = v; bi1 = f; }
  }
  sv[0][tid] = bv0; si[0][tid] = bi0;
  sv[1][tid] = bv1; si[1][tid] = bi1;
  __syncthreads();
  for (int off = 128; off > 0; off >>= 1) {
    if (tid < off) {
#pragma unroll
      for (int q = 0; q < 2; ++q) {
        float v2 = sv[q][tid + off];
        int i2 = si[q][tid + off];
        if (v2 > sv[q][tid] || (v2 == sv[q][tid] && i2 < si[q][tid])) {
          sv[q][tid] = v2; si[q][tid] = i2;
        }
      }
    }
    __syncthreads();
  }
  if (tid == 0) {
    segv[(0 * 512 + t) * NSEG + seg] = sv[0][0];
    segi[(0 * 512 + t) * NSEG + seg] = si[0][0];
    segv[(1 * 512 + t) * NSEG + seg] = sv[1][0];
    segi[(1 * 512 + t) * NSEG + seg] = si[1][0];
  }
}

__global__ void cat_reduce_kernel(const float* __restrict__ segv,
                                  const int* __restrict__ segi,
                                  int* __restrict__ m_flat) {
  const int idx = blockIdx.x * 256 + threadIdx.x;  // 0..1023 = b*512 + t
  if (idx >= NB * 512) return;
  float bv = -1e30f;
  int bi = IJ;
#pragma unroll
  for (int s = 0; s < NSEG; ++s) {
    float v = segv[idx * NSEG + s];
    int i = segi[idx * NSEG + s];
    if (v > bv || (v == bv && i < bi)) { bv = v; bi = i; }
  }
  m_flat[idx] = bi;
}

// ---------------- pose hypotheses (R, t) -----------------------------------
__global__ void pose_kernel(const float* __restrict__ q_xy,
                            const int* __restrict__ n_idx,
                            const int* __restrict__ m_flat,
                            float4* __restrict__ poses) {
  const int idx = blockIdx.x * 256 + threadIdx.x;  // 0..511
  if (idx >= NB * KP) return;
  const int b = idx >> 8, k = idx & 255;
  const int t0 = b * 512 + 2 * k, t1 = t0 + 1;
  const int na = n_idx[t0], nb = n_idx[t1];
  const float2 q0 = ((const float2*)q_xy)[(size_t)b * NQ + na];
  const float2 q1 = ((const float2*)q_xy)[(size_t)b * NQ + nb];
  const int ma = m_flat[t0], mb = m_flat[t1];
  const float m0x = ((float)(ma >> 7) + 0.5f) * 0.5f;
  const float m0y = ((float)(ma & 127) + 0.5f) * 0.5f;
  const float m1x = ((float)(mb >> 7) + 0.5f) * 0.5f;
  const float m1y = ((float)(mb & 127) + 0.5f) * 0.5f;
  const float dqx = q1.x - q0.x, dqy = q1.y - q0.y;
  const float dmx = m1x - m0x, dmy = m1y - m0y;
  const float theta = atan2f(dmy, dmx) - atan2f(dqy, dqx);
  const float c = cosf(theta), s = sinf(theta);
  const float tx = m0x - (c * q0.x - s * q0.y);
  const float ty = m0y - (s * q0.x + c * q0.y);
  poses[idx] = make_float4(c, s, tx, ty);
}

// ---------------- score every pose -----------------------------------------
__global__ __launch_bounds__(256) void score_kernel(
    const float* __restrict__ sim, const float* __restrict__ q_xy,
    const void* __restrict__ valid_q, const void* __restrict__ valid_map,
    const float* __restrict__ num_valid, const float4* __restrict__ poses,
    const int* __restrict__ bool_is32, float* __restrict__ out) {
  __shared__ float sred[256];
  const int idx = blockIdx.x;  // b*256 + k
  const int tid = threadIdx.x;
  const int b = idx >> 8;
  const int is32 = bool_is32[0];
  const float4 P = poses[idx];
  float acc = 0.f;
  for (int n = tid; n < NQ; n += 256) {
    float2 q = ((const float2*)q_xy)[(size_t)b * NQ + n];
    float px = P.x * q.x - P.y * q.y + P.z;
    float py = P.y * q.x + P.x * q.y + P.w;
    int ii = (int)floorf(px * 2.0f);  // / CELL (=0.5) is exact *2
    int jj = (int)floorf(py * 2.0f);
    bool inb = (ii >= 0) & (ii < 128) & (jj >= 0) & (jj < 128);
    int ic = min(max(ii, 0), 127), jc = min(max(jj, 0), 127);
    int flat = (ic << 7) + jc;
    bool msk = read_bool(valid_q, b * NQ + n, is32) && inb &&
               read_bool(valid_map, b * IJ + flat, is32);
    if (msk) acc += sim[((size_t)(b * NQ + n)) * IJ + flat];
  }
  sred[tid] = acc;
  __syncthreads();
  for (int off = 128; off > 0; off >>= 1) {
    if (tid < off) sred[tid] += sred[tid + off];
    __syncthreads();
  }
  if (tid == 0) out[idx] = sred[0] / num_valid[b];
}

// ---------------------------------------------------------------------------
extern "C" void kernel_launch(void* const* d_in, const int* in_sizes, int n_in,
                              void* d_out, int out_size, void* d_ws,
                              size_t ws_size, hipStream_t stream) {
  const float* f_q = (const float*)d_in[0];
  const float* f_map = (const float*)d_in[1];
  const float* q_xy = (const float*)d_in[2];
  const float* temp = (const float*)d_in[3];
  const void* valid_q = d_in[4];    // numpy bool: width auto-detected
  const void* valid_map = d_in[5];  // numpy bool: width auto-detected
  const int* seedp = (const int*)d_in[6];
  float* out = (float*)d_out;

  char* ws = (char*)d_ws;
  const size_t SIM_BYTES = (size_t)NB * NQ * IJ * 4;  // 134217728
  float* sim = (float*)ws;
  float* row_max = (float*)(ws + SIM_BYTES);
  float* row_sumexp = (float*)(ws + SIM_BYTES + 8192);
  float* num_valid = (float*)(ws + SIM_BYTES + 16384);
  int* n_idx = (int*)(ws + SIM_BYTES + 16448);
  int* m_flat = (int*)(ws + SIM_BYTES + 20544);
  float4* poses = (float4*)(ws + SIM_BYTES + 24640);
  int* bool_is32 = (int*)(ws + SIM_BYTES + 32832);
  float* segv = (float*)(ws + SIM_BYTES + 36864);       // 32 KB
  int* segi = (int*)(ws + SIM_BYTES + 69632);           // 32 KB
  float* rowsum_part = (float*)(ws + SIM_BYTES + 102400);  // 2048*64 f32 = 512 KB

  setup_kernel<<<8, 256, 0, stream>>>(valid_q, seedp, row_max, num_valid,
                                      n_idx, bool_is32);
  gemm_kernel<<<dim3(64, 16, 2), 256, 0, stream>>>(f_q, f_map, temp, sim,
                                                   row_max, rowsum_part);
  sumexp_reduce_kernel<<<8, 256, 0, stream>>>(rowsum_part, row_max, row_sumexp);
  cat_seg_kernel<<<dim3(NSEG, 512), 256, 0, stream>>>(
      sim, row_max, row_sumexp, num_valid, n_idx, seedp, segv, segi);
  cat_reduce_kernel<<<4, 256, 0, stream>>>(segv, segi, m_flat);
  pose_kernel<<<2, 256, 0, stream>>>(q_xy, n_idx, m_flat, poses);
  score_kernel<<<NB * KP, 256, 0, stream>>>(sim, q_xy, valid_q, valid_map,
                                            num_valid, poses, bool_is32, out);
}